// Round 11
// baseline (626.613 us; speedup 1.0000x reference)
//
#include <hip/hip_runtime.h>
#include <hip/hip_bf16.h>

#define N_NODES 32768
#define N_GRAPHS 8
#define NPG 4096
#define DEG 8
#define N_EDGES (N_NODES*DEG)
#define TW 25
#define NL 6
#define L_PDE 16.0f
#define TMAXC 4.0f
#define DTC 0.04f
#define EPSC 1e-5f

typedef __bf16 bf16x8 __attribute__((ext_vector_type(8)));
typedef float f32x4 __attribute__((ext_vector_type(4)));
typedef unsigned short u16;
typedef unsigned int u32;

__device__ __forceinline__ float bf2f(u16 h){
  union { float f; u32 u; } v; v.u = ((u32)h) << 16; return v.f;
}
__device__ __forceinline__ u16 f2bf(float f){
  union { float f; u32 u; } v; v.f = f;
  u32 r = v.u + 0x7FFFu + ((v.u >> 16) & 1u);
  return (u16)(r >> 16);
}
// swish via v_rcp_f32 (~1ulp) instead of IEEE divide.
__device__ __forceinline__ float swishf(float x){
  return x * __builtin_amdgcn_rcpf(1.0f + __expf(-x));
}

// ---------------------------------------------------------------------------
// Weight prep: repack W[K][N] (f32, k-major) into frag-major bf16.
// ---------------------------------------------------------------------------
__global__ void prep_std(const float* __restrict__ src, u16* __restrict__ dst,
                         int Ksrc, int KPAD, int NOUT)
{
  int l = blockIdx.y;
  int per = KPAD * NOUT;
  int i = blockIdx.x * 256 + threadIdx.x;
  if (i >= per) return;
  int KSTEPS = KPAD / 32;
  int e = i & 7;
  int lane = (i >> 3) & 63;
  int ks = (i >> 9) % KSTEPS;
  int nf = i / (KSTEPS * 512);
  int c = nf * 16 + (lane & 15);
  int k = ks * 32 + (lane >> 4) * 8 + e;
  float v = (k < Ksrc) ? src[(size_t)l * Ksrc * NOUT + (size_t)k * NOUT + c] : 0.f;
  dst[(size_t)l * per + i] = f2bf(v);
}

// AB factorization weights (see earlier rounds).
__global__ void prep_AB(const float* __restrict__ W, const float* __restrict__ bsrc,
                        u16* __restrict__ dst, float* __restrict__ bdst)
{
  int l = blockIdx.y;
  const int KSTEPS = 6;
  int i = blockIdx.x * 256 + threadIdx.x;       // < 192*256 = 49152
  int e = i & 7, lane = (i >> 3) & 63, ks = (i >> 9) % KSTEPS, nf = i / (KSTEPS * 512);
  int c = nf * 16 + (lane & 15);
  int k = ks * 32 + (lane >> 4) * 8 + e;
  const float* Wl = W + (size_t)l * 308 * 128;
  float v = 0.f;
  if (c < 128) {
    int rowi = -1;
    if (k < 128) rowi = k;
    else if (k < 178) rowi = 256 + (k - 128);
    else if (k == 178) rowi = 306;
    else if (k == 179) rowi = 307;
    if (rowi >= 0) v = Wl[rowi * 128 + c];
  } else {
    int cc = c - 128; float sgn = 1.f; int rowi = -1;
    if (k < 128) rowi = 128 + k;
    else if (k < 178) { rowi = 256 + (k - 128); sgn = -1.f; }
    else if (k == 178) { rowi = 306; sgn = -1.f; }
    if (rowi >= 0) v = sgn * Wl[rowi * 128 + cc];
  }
  dst[(size_t)l * 192 * 256 + i] = f2bf(v);
  if (i < 256) bdst[l * 256 + i] = (i < 128) ? bsrc[l * 128 + i] : 0.f;
}

// Static feature columns: X0[N][64] = [u(50), px, pt, 0..]
__global__ __launch_bounds__(256) void build_static(
    const float* __restrict__ u, const float* __restrict__ pos,
    u16* __restrict__ X0)
{
  int idx = blockIdx.x * 256 + threadIdx.x;   // N*64
  int n = idx >> 6, j = idx & 63;
  float v;
  if (j < 50) v = u[n * 50 + j];
  else if (j == 50) v = pos[n * 2 + 1] * (1.f / L_PDE);
  else if (j == 51) v = pos[n * 2 + 0] * (1.f / TMAXC);
  else v = 0.f;
  X0[n * 64 + j] = f2bf(v);
}

// ---------------------------------------------------------------------------
// Unified MFMA GEMM (used for AB and dbl). Col-split wave layout.
// SMODE: 1 = [norm(hB,statsPrev) (128) | X0 static (KPAD-128)]
// ---------------------------------------------------------------------------
template<int KPAD, int NOUT, int ACT, int SMODE, int RESID, int HASOUT>
__global__ __launch_bounds__(256) void gemm2(
    const u16* __restrict__ X, int ldx,
    const u16* __restrict__ Xaux,
    float* hB,
    const float* __restrict__ S1p, const float* __restrict__ S2p,
    const float* __restrict__ pos,
    const u16* __restrict__ Wf, const float* __restrict__ bias,
    u16* __restrict__ out, int ldo,
    float* __restrict__ outF,
    float* __restrict__ S1n, float* __restrict__ S2n)
{
  constexpr int KSTEPS = KPAD / 32;
  constexpr int NF2 = NOUT / 32;
  constexpr int CHUNKS = KPAD / 8;
  constexpr int LDO_S = NOUT + 8;
  constexpr int SMEM_US = 64 * (HASOUT ? (KPAD > LDO_S ? KPAD : LDO_S) : KPAD);
  __shared__ u16 sm[SMEM_US];
  int tid = threadIdx.x, lane = tid & 63, wid = tid >> 6;
  int n0 = blockIdx.x * 64;
  int g = n0 >> 12;

  for (int c = tid; c < 64 * CHUNKS; c += 256) {
    int r = c / CHUNKS, kc = c % CHUNKS;
    int n = n0 + r;
    union { uint4 v; u16 s[8]; } o;
    if (SMODE == 0) {
      o.v = *(const uint4*)(X + (size_t)n * ldx + kc * 8);
    } else {
      if (kc < 16) {
        const float* hp = hB + (size_t)n * 128 + kc * 8;
        float4 a0 = *(const float4*)hp, a1 = *(const float4*)(hp + 4);
        float xv[8] = {a0.x,a0.y,a0.z,a0.w,a1.x,a1.y,a1.z,a1.w};
        if (S1p) {
          #pragma unroll
          for (int j = 0; j < 8; ++j) {
            int cc = kc * 8 + j;
            float m = S1p[g * 128 + cc] * (1.f / NPG);
            float var = S2p[g * 128 + cc] * (1.f / NPG) - m * m;
            xv[j] = (xv[j] - m) * rsqrtf(var + EPSC);
          }
        }
        #pragma unroll
        for (int j = 0; j < 8; ++j) o.s[j] = f2bf(xv[j]);
      } else {
        o.v = *(const uint4*)(Xaux + (size_t)n * 64 + (kc - 16) * 8);
      }
    }
    int byte = r * (KPAD * 2) + kc * 16; byte ^= ((r & 7) << 4);
    *(uint4*)((char*)sm + byte) = o.v;
  }
  __syncthreads();

  int rowHalf = wid & 1, colHalf = wid >> 1;
  f32x4 acc[2][NF2];
  f32x4 zero = {0.f, 0.f, 0.f, 0.f};
  #pragma unroll
  for (int m = 0; m < 2; ++m)
    #pragma unroll
    for (int i = 0; i < NF2; ++i) acc[m][i] = zero;
  int rowA = rowHalf * 32 + (lane & 15);
  int kb = lane >> 4;
  #pragma unroll
  for (int ks = 0; ks < KSTEPS; ++ks) {
    int ab0 = rowA * (KPAD * 2) + ks * 64 + kb * 16; ab0 ^= ((rowA & 7) << 4);
    int rA1 = rowA + 16;
    int ab1 = rA1 * (KPAD * 2) + ks * 64 + kb * 16; ab1 ^= ((rA1 & 7) << 4);
    bf16x8 a0 = *(const bf16x8*)((const char*)sm + ab0);
    bf16x8 a1 = *(const bf16x8*)((const char*)sm + ab1);
    #pragma unroll
    for (int nf2 = 0; nf2 < NF2; ++nf2) {
      bf16x8 b = *(const bf16x8*)(Wf + (((colHalf * NF2 + nf2) * KSTEPS + ks) * 64 + lane) * 8);
      acc[0][nf2] = __builtin_amdgcn_mfma_f32_16x16x32_bf16(a0, b, acc[0][nf2], 0, 0, 0);
      acc[1][nf2] = __builtin_amdgcn_mfma_f32_16x16x32_bf16(a1, b, acc[1][nf2], 0, 0, 0);
    }
  }

  if (HASOUT) __syncthreads();
  #pragma unroll
  for (int nf2 = 0; nf2 < NF2; ++nf2) {
    int col = colHalf * (NOUT / 2) + nf2 * 16 + (lane & 15);
    float bv = bias[col];
    #pragma unroll
    for (int m = 0; m < 2; ++m)
      #pragma unroll
      for (int j = 0; j < 4; ++j) {
        int r = rowHalf * 32 + m * 16 + (lane >> 4) * 4 + j;
        float v = acc[m][nf2][j] + bv;
        if (ACT == 1) v = swishf(v);
        if (HASOUT) sm[r * LDO_S + col] = f2bf(v);
        if (outF) outF[(size_t)(n0 + r) * NOUT + col] = v;
      }
  }
  if (HASOUT) {
    __syncthreads();
    for (int c = tid; c < 64 * NOUT / 8; c += 256) {
      int r = c / (NOUT / 8), kc = c % (NOUT / 8);
      uint4 v = *(const uint4*)(sm + r * LDO_S + kc * 8);
      *(uint4*)(out + (size_t)(n0 + r) * ldo + kc * 8) = v;
    }
  }
}

// ---------------------------------------------------------------------------
// Fused encoder: h = swish(swish(X0@W1+b1)@W2+b2) -> hB (f32).
// ---------------------------------------------------------------------------
__global__ __launch_bounds__(256) void enc_fused(
    const u16* __restrict__ X0,
    const u16* __restrict__ W1f, const float* __restrict__ b1,
    const u16* __restrict__ W2f, const float* __restrict__ b2,
    float* __restrict__ hB)
{
  __shared__ u16 s1[64 * 64];
  __shared__ u16 s2[64 * 128];
  int tid = threadIdx.x, lane = tid & 63, wid = tid >> 6;
  int n0 = blockIdx.x * 64;

  for (int c = tid; c < 64 * 8; c += 256) {
    int r = c >> 3, kc = c & 7;
    uint4 v = *(const uint4*)(X0 + (size_t)(n0 + r) * 64 + kc * 8);
    int byte = r * 128 + kc * 16; byte ^= ((r & 7) << 4);
    *(uint4*)((char*)s1 + byte) = v;
  }
  __syncthreads();

  int rowHalf = wid & 1, colHalf = wid >> 1;
  int rowA = rowHalf * 32 + (lane & 15), kb = lane >> 4;
  f32x4 acc[2][4];
  f32x4 zero = {0.f, 0.f, 0.f, 0.f};
  #pragma unroll
  for (int m = 0; m < 2; ++m)
    #pragma unroll
    for (int i = 0; i < 4; ++i) acc[m][i] = zero;
  #pragma unroll
  for (int ks = 0; ks < 2; ++ks) {
    int ab0 = rowA * 128 + ks * 64 + kb * 16; ab0 ^= ((rowA & 7) << 4);
    int rA1 = rowA + 16;
    int ab1 = rA1 * 128 + ks * 64 + kb * 16; ab1 ^= ((rA1 & 7) << 4);
    bf16x8 a0 = *(const bf16x8*)((const char*)s1 + ab0);
    bf16x8 a1 = *(const bf16x8*)((const char*)s1 + ab1);
    #pragma unroll
    for (int nf2 = 0; nf2 < 4; ++nf2) {
      bf16x8 b = *(const bf16x8*)(W1f + (((colHalf * 4 + nf2) * 2 + ks) * 64 + lane) * 8);
      acc[0][nf2] = __builtin_amdgcn_mfma_f32_16x16x32_bf16(a0, b, acc[0][nf2], 0, 0, 0);
      acc[1][nf2] = __builtin_amdgcn_mfma_f32_16x16x32_bf16(a1, b, acc[1][nf2], 0, 0, 0);
    }
  }
  #pragma unroll
  for (int nf2 = 0; nf2 < 4; ++nf2) {
    int col = colHalf * 64 + nf2 * 16 + (lane & 15);
    float bv = b1[col];
    #pragma unroll
    for (int m = 0; m < 2; ++m)
      #pragma unroll
      for (int j = 0; j < 4; ++j) {
        int r = rowHalf * 32 + m * 16 + (lane >> 4) * 4 + j;
        int byte = r * 256 + col * 2; byte ^= ((r & 7) << 4);
        *(u16*)((char*)s2 + byte) = f2bf(swishf(acc[m][nf2][j] + bv));
      }
  }
  __syncthreads();
  #pragma unroll
  for (int m = 0; m < 2; ++m)
    #pragma unroll
    for (int i = 0; i < 4; ++i) acc[m][i] = zero;
  #pragma unroll
  for (int ks = 0; ks < 4; ++ks) {
    int ab0 = rowA * 256 + ks * 64 + kb * 16; ab0 ^= ((rowA & 7) << 4);
    int rA1 = rowA + 16;
    int ab1 = rA1 * 256 + ks * 64 + kb * 16; ab1 ^= ((rA1 & 7) << 4);
    bf16x8 a0 = *(const bf16x8*)((const char*)s2 + ab0);
    bf16x8 a1 = *(const bf16x8*)((const char*)s2 + ab1);
    #pragma unroll
    for (int nf2 = 0; nf2 < 4; ++nf2) {
      bf16x8 b = *(const bf16x8*)(W2f + (((colHalf * 4 + nf2) * 4 + ks) * 64 + lane) * 8);
      acc[0][nf2] = __builtin_amdgcn_mfma_f32_16x16x32_bf16(a0, b, acc[0][nf2], 0, 0, 0);
      acc[1][nf2] = __builtin_amdgcn_mfma_f32_16x16x32_bf16(a1, b, acc[1][nf2], 0, 0, 0);
    }
  }
  #pragma unroll
  for (int nf2 = 0; nf2 < 4; ++nf2) {
    int col = colHalf * 64 + nf2 * 16 + (lane & 15);
    float bv = b2[col];
    #pragma unroll
    for (int m = 0; m < 2; ++m)
      #pragma unroll
      for (int j = 0; j < 4; ++j) {
        int r = rowHalf * 32 + m * 16 + (lane >> 4) * 4 + j;
        hB[(size_t)(n0 + r) * 128 + col] = swishf(acc[m][nf2][j] + bv);
      }
  }
}

// ---------------------------------------------------------------------------
// FUSED msg + update MLP. One block = 64 nodes = 512 edges.
// Phase A (x8 subtiles of 64 edges): m=swish(A[dst]+B[src]) -> Ms;
//   m2 = swish(m@Wm2+b); mean over 8 edges -> agg -> s1 cols 128..255 (bf16).
// Phase B: z = swish(s1 @ Wu1 + b1) -> s2; up = swish(z @ Wu2 + b2);
//   hn = norm(hB) + up -> hB; per-(graph,col) moment atomics.
// ---------------------------------------------------------------------------
__global__ __launch_bounds__(256) void msg_upd(
    const u16* __restrict__ AB, const int* __restrict__ srcIdx,
    float* hB,
    const float* __restrict__ S1p, const float* __restrict__ S2p,
    const float* __restrict__ pos,
    const u16* __restrict__ Wmf, const float* __restrict__ bm2,
    const u16* __restrict__ W1f, const float* __restrict__ b1,
    const u16* __restrict__ W2f, const float* __restrict__ b2,
    float* __restrict__ S1n, float* __restrict__ S2n)
{
  __shared__ u16 s1[64 * 320];     // [norm(hB) | agg | pt,0..] swizzled, 40KB
  __shared__ u16 Ms[64 * 128];     // per-subtile m tile, 16KB
  __shared__ u16 s2[64 * 128];     // z, 16KB
  __shared__ float aggS[8][132];   // 4.2KB
  int tid = threadIdx.x, lane = tid & 63, wid = tid >> 6;
  int n0 = blockIdx.x * 64;
  int g = n0 >> 12;

  // stage h-part (kc<16) and pt/zero (kc>=32); agg cols filled by subtiles
  for (int c = tid; c < 64 * 40; c += 256) {
    int r = c / 40, kc = c % 40;
    if (kc >= 16 && kc < 32) continue;
    int n = n0 + r;
    union { uint4 v; u16 s[8]; } o;
    if (kc < 16) {
      const float* hp = hB + (size_t)n * 128 + kc * 8;
      float4 a0 = *(const float4*)hp, a1 = *(const float4*)(hp + 4);
      float xv[8] = {a0.x,a0.y,a0.z,a0.w,a1.x,a1.y,a1.z,a1.w};
      if (S1p) {
        #pragma unroll
        for (int j = 0; j < 8; ++j) {
          int cc = kc * 8 + j;
          float m = S1p[g * 128 + cc] * (1.f / NPG);
          float var = S2p[g * 128 + cc] * (1.f / NPG) - m * m;
          xv[j] = (xv[j] - m) * rsqrtf(var + EPSC);
        }
      }
      #pragma unroll
      for (int j = 0; j < 8; ++j) o.s[j] = f2bf(xv[j]);
    } else {
      #pragma unroll
      for (int j = 0; j < 8; ++j) o.s[j] = 0;
      if (kc == 32) o.s[0] = f2bf(pos[n * 2] * (1.f / TMAXC));
    }
    int byte = r * 640 + kc * 16; byte ^= ((r & 7) << 4);
    *(uint4*)((char*)s1 + byte) = o.v;
  }

  int rowHalf = wid & 1, colHalf = wid >> 1;
  int rowA = rowHalf * 32 + (lane & 15), kb = lane >> 4;
  f32x4 zero = {0.f, 0.f, 0.f, 0.f};

  // Phase A: 8 subtiles of 64 edges
  for (int st = 0; st < 8; ++st) {
    __syncthreads();   // Ms/aggS reuse + prior conversion complete
    int e0 = n0 * 8 + st * 64;
    for (int c = tid; c < 1024; c += 256) {
      int i = c >> 4, kc = c & 15;
      int e = e0 + i;
      int nd = e >> 3;
      int ns = srcIdx[e];
      union { uint4 v; u16 s[8]; } va, vb, vo;
      va.v = *(const uint4*)(AB + (size_t)nd * 256 + kc * 8);
      vb.v = *(const uint4*)(AB + (size_t)ns * 256 + 128 + kc * 8);
      #pragma unroll
      for (int j = 0; j < 8; ++j) vo.s[j] = f2bf(swishf(bf2f(va.s[j]) + bf2f(vb.s[j])));
      int byte = i * 256 + kc * 16; byte ^= ((i & 7) << 4);
      *(uint4*)((char*)Ms + byte) = vo.v;
    }
    __syncthreads();
    {
      f32x4 acc[2][4];
      #pragma unroll
      for (int m = 0; m < 2; ++m)
        #pragma unroll
        for (int i = 0; i < 4; ++i) acc[m][i] = zero;
      #pragma unroll
      for (int ks = 0; ks < 4; ++ks) {
        int ab0 = rowA * 256 + ks * 64 + kb * 16; ab0 ^= ((rowA & 7) << 4);
        int rA1 = rowA + 16;
        int ab1 = rA1 * 256 + ks * 64 + kb * 16; ab1 ^= ((rA1 & 7) << 4);
        bf16x8 a0 = *(const bf16x8*)((const char*)Ms + ab0);
        bf16x8 a1 = *(const bf16x8*)((const char*)Ms + ab1);
        #pragma unroll
        for (int nf2 = 0; nf2 < 4; ++nf2) {
          bf16x8 b = *(const bf16x8*)(Wmf + (((colHalf * 4 + nf2) * 4 + ks) * 64 + lane) * 8);
          acc[0][nf2] = __builtin_amdgcn_mfma_f32_16x16x32_bf16(a0, b, acc[0][nf2], 0, 0, 0);
          acc[1][nf2] = __builtin_amdgcn_mfma_f32_16x16x32_bf16(a1, b, acc[1][nf2], 0, 0, 0);
        }
      }
      #pragma unroll
      for (int m = 0; m < 2; ++m)
        #pragma unroll
        for (int nf2 = 0; nf2 < 4; ++nf2) {
          int col = colHalf * 64 + nf2 * 16 + (lane & 15);
          float bv = bm2[col];
          float s = 0.f;
          #pragma unroll
          for (int j = 0; j < 4; ++j) s += swishf(acc[m][nf2][j] + bv);
          s += __shfl_xor(s, 16);
          if ((lane & 31) < 16)
            aggS[rowHalf * 4 + m * 2 + (lane >> 5)][col] = s * 0.125f;
        }
    }
    __syncthreads();
    {
      int node = tid >> 5;
      int c0 = (tid & 31) * 4;
      int r = st * 8 + node;
      ushort4 o;
      o.x = f2bf(aggS[node][c0 + 0]);
      o.y = f2bf(aggS[node][c0 + 1]);
      o.z = f2bf(aggS[node][c0 + 2]);
      o.w = f2bf(aggS[node][c0 + 3]);
      int byte = r * 640 + (128 + c0) * 2; byte ^= ((r & 7) << 4);
      *(ushort4*)((char*)s1 + byte) = o;
    }
  }
  __syncthreads();

  // Phase B: update MLP
  f32x4 acc[2][4];
  #pragma unroll
  for (int m = 0; m < 2; ++m)
    #pragma unroll
    for (int i = 0; i < 4; ++i) acc[m][i] = zero;
  #pragma unroll
  for (int ks = 0; ks < 10; ++ks) {
    int ab0 = rowA * 640 + ks * 64 + kb * 16; ab0 ^= ((rowA & 7) << 4);
    int rA1 = rowA + 16;
    int ab1 = rA1 * 640 + ks * 64 + kb * 16; ab1 ^= ((rA1 & 7) << 4);
    bf16x8 a0 = *(const bf16x8*)((const char*)s1 + ab0);
    bf16x8 a1 = *(const bf16x8*)((const char*)s1 + ab1);
    #pragma unroll
    for (int nf2 = 0; nf2 < 4; ++nf2) {
      bf16x8 b = *(const bf16x8*)(W1f + (((colHalf * 4 + nf2) * 10 + ks) * 64 + lane) * 8);
      acc[0][nf2] = __builtin_amdgcn_mfma_f32_16x16x32_bf16(a0, b, acc[0][nf2], 0, 0, 0);
      acc[1][nf2] = __builtin_amdgcn_mfma_f32_16x16x32_bf16(a1, b, acc[1][nf2], 0, 0, 0);
    }
  }
  #pragma unroll
  for (int nf2 = 0; nf2 < 4; ++nf2) {
    int col = colHalf * 64 + nf2 * 16 + (lane & 15);
    float bv = b1[col];
    #pragma unroll
    for (int m = 0; m < 2; ++m)
      #pragma unroll
      for (int j = 0; j < 4; ++j) {
        int r = rowHalf * 32 + m * 16 + (lane >> 4) * 4 + j;
        int byte = r * 256 + col * 2; byte ^= ((r & 7) << 4);
        *(u16*)((char*)s2 + byte) = f2bf(swishf(acc[m][nf2][j] + bv));
      }
  }
  __syncthreads();
  #pragma unroll
  for (int m = 0; m < 2; ++m)
    #pragma unroll
    for (int i = 0; i < 4; ++i) acc[m][i] = zero;
  #pragma unroll
  for (int ks = 0; ks < 4; ++ks) {
    int ab0 = rowA * 256 + ks * 64 + kb * 16; ab0 ^= ((rowA & 7) << 4);
    int rA1 = rowA + 16;
    int ab1 = rA1 * 256 + ks * 64 + kb * 16; ab1 ^= ((rA1 & 7) << 4);
    bf16x8 a0 = *(const bf16x8*)((const char*)s2 + ab0);
    bf16x8 a1 = *(const bf16x8*)((const char*)s2 + ab1);
    #pragma unroll
    for (int nf2 = 0; nf2 < 4; ++nf2) {
      bf16x8 b = *(const bf16x8*)(W2f + (((colHalf * 4 + nf2) * 4 + ks) * 64 + lane) * 8);
      acc[0][nf2] = __builtin_amdgcn_mfma_f32_16x16x32_bf16(a0, b, acc[0][nf2], 0, 0, 0);
      acc[1][nf2] = __builtin_amdgcn_mfma_f32_16x16x32_bf16(a1, b, acc[1][nf2], 0, 0, 0);
    }
  }
  float s1l[4], s2l[4];
  #pragma unroll
  for (int i = 0; i < 4; ++i) { s1l[i] = 0.f; s2l[i] = 0.f; }
  #pragma unroll
  for (int nf2 = 0; nf2 < 4; ++nf2) {
    int col = colHalf * 64 + nf2 * 16 + (lane & 15);
    float bv = b2[col];
    float mm = 0.f, rsig = 1.f;
    if (S1p) {
      mm = S1p[g * 128 + col] * (1.f / NPG);
      float var = S2p[g * 128 + col] * (1.f / NPG) - mm * mm;
      rsig = rsqrtf(var + EPSC);
    }
    #pragma unroll
    for (int m = 0; m < 2; ++m)
      #pragma unroll
      for (int j = 0; j < 4; ++j) {
        int r = rowHalf * 32 + m * 16 + (lane >> 4) * 4 + j;
        int n = n0 + r;
        float v = swishf(acc[m][nf2][j] + bv);
        float hc = hB[(size_t)n * 128 + col];
        hc = (hc - mm) * rsig;
        float hn = hc + v;
        hB[(size_t)n * 128 + col] = hn;
        s1l[nf2] += hn; s2l[nf2] += hn * hn;
      }
  }
  #pragma unroll
  for (int nf2 = 0; nf2 < 4; ++nf2) {
    float s1v = s1l[nf2], s2v = s2l[nf2];
    s1v += __shfl_xor(s1v, 16); s1v += __shfl_xor(s1v, 32);
    s2v += __shfl_xor(s2v, 16); s2v += __shfl_xor(s2v, 32);
    if ((lane >> 4) == 0) {
      int col = colHalf * 64 + nf2 * 16 + (lane & 15);
      atomicAdd(&S1n[g * 128 + col], s1v);
      atomicAdd(&S2n[g * 128 + col], s2v);
    }
  }
}

// ---------------------------------------------------------------------------
// Decoder: phase-split x layout, register windows, contiguous t-chunks.
// ---------------------------------------------------------------------------
__global__ __launch_bounds__(256) void dec_conv(
    const float* __restrict__ x2f, const float* __restrict__ u,
    const float* __restrict__ w1, const float* __restrict__ b1,
    const float* __restrict__ w2, const float* __restrict__ b2,
    float* __restrict__ outp)
{
  __shared__ float xs3[2][3][16][44];
  __shared__ float ys[16][8][41];
  __shared__ float w1s[256], w2s[224];
  int tid = threadIdx.x;
  int n0 = blockIdx.x * 16;

  w1s[tid] = w1[tid];
  if (tid < 224) w2s[tid] = w2[tid];
  for (int i = tid; i < 16 * 64; i += 256) {
    int r = i >> 6, cq = i & 63;
    int cc = cq >> 5;
    int j4 = (cq & 31) * 4;
    float4 v = *(const float4*)(x2f + (size_t)(n0 + r) * 256 + cc * 128 + j4);
    float xe[4] = {v.x, v.y, v.z, v.w};
    #pragma unroll
    for (int e = 0; e < 4; ++e) {
      int j = j4 + e;
      xs3[cc][j % 3][r][j / 3] = xe[e];
    }
  }
  __syncthreads();

  {
    int n = tid >> 4, o = (tid >> 1) & 7, th = tid & 1;
    int t0 = th * 19;
    float y[19];
    float b1v = b1[o];
    #pragma unroll
    for (int t = 0; t < 19; ++t) y[t] = b1v;
    #pragma unroll
    for (int cc = 0; cc < 2; ++cc) {
      #pragma unroll
      for (int p = 0; p < 3; ++p) {
        const int KP = (p == 0) ? 6 : 5;
        float wr[6];
        #pragma unroll
        for (int k = 0; k < KP; ++k) wr[k] = w1s[o * 32 + cc * 16 + 3 * k + p];
        float win[24];
        #pragma unroll
        for (int q = 0; q < 18 + KP; ++q) win[q] = xs3[cc][p][n][t0 + q];
        #pragma unroll
        for (int t = 0; t < 19; ++t)
          #pragma unroll
          for (int k = 0; k < KP; ++k)
            y[t] += win[t + k] * wr[k];
      }
    }
    #pragma unroll
    for (int t = 0; t < 19; ++t) ys[n][o][t0 + t] = swishf(y[t]);
  }
  __syncthreads();

  {
    int n = tid >> 4, c = (tid >> 3) & 1, ts = tid & 7;
    int t0 = (ts == 0) ? 0 : ts * 3 + 1;
    int lim = (ts == 0) ? 4 : 3;
    float b2v = b2[c];
    float acc[4] = {b2v, b2v, b2v, b2v};
    #pragma unroll
    for (int ic = 0; ic < 8; ++ic) {
      float wr[14];
      #pragma unroll
      for (int k = 0; k < 14; ++k) wr[k] = w2s[c * 112 + ic * 14 + k];
      float win[17];
      #pragma unroll
      for (int q = 0; q < 17; ++q) win[q] = ys[n][ic][t0 + q];
      #pragma unroll
      for (int t = 0; t < 4; ++t)
        #pragma unroll
        for (int k = 0; k < 14; ++k)
          acc[t] += win[t + k] * wr[k];
    }
    #pragma unroll
    for (int t = 0; t < 4; ++t) {
      if (t < lim) {
        int tt = t0 + t;
        int gi = (n0 + n) * 50 + c * 25 + tt;
        outp[gi] = u[gi] + (DTC * (tt + 1)) * acc[t];
      }
    }
  }
}

extern "C" void kernel_launch(void* const* d_in, const int* in_sizes, int n_in,
                              void* d_out, int out_size, void* d_ws, size_t ws_size,
                              hipStream_t stream) {
  const float* u     = (const float*)d_in[0];
  const float* pos   = (const float*)d_in[1];
  const int*   eidx  = (const int*)d_in[2];
  const float* embW1 = (const float*)d_in[4];
  const float* embb1 = (const float*)d_in[5];
  const float* embW2 = (const float*)d_in[6];
  const float* embb2 = (const float*)d_in[7];
  const float* m1W   = (const float*)d_in[8];
  const float* m1b   = (const float*)d_in[9];
  const float* m2W   = (const float*)d_in[10];
  const float* m2b   = (const float*)d_in[11];
  const float* u1W   = (const float*)d_in[12];
  const float* u1b   = (const float*)d_in[13];
  const float* u2W   = (const float*)d_in[14];
  const float* u2b   = (const float*)d_in[15];
  const float* dblW  = (const float*)d_in[16];
  const float* dblb  = (const float*)d_in[17];
  const float* c1W   = (const float*)d_in[18];
  const float* c1b   = (const float*)d_in[19];
  const float* c2W   = (const float*)d_in[20];
  const float* c2b   = (const float*)d_in[21];
  float* outp = (float*)d_out;
  const int* srcI = eidx;   // edge_index[0] = src; dst(e) = e>>3 by construction

  char* ws = (char*)d_ws;
  size_t off = 0;
  auto alloc = [&](size_t bytes) -> char* {
    char* p = ws + off; off += (bytes + 255) & ~(size_t)255; return p;
  };
  u16* X0    = (u16*)alloc((size_t)N_NODES * 64 * 2);
  u16* ABbuf = (u16*)alloc((size_t)N_NODES * 256 * 2);
  float* hB  = (float*)alloc((size_t)N_NODES * 128 * 4);
  float* x2f = (float*)alloc((size_t)N_NODES * 256 * 4);
  float* stats = (float*)alloc((size_t)NL * 2 * 1024 * 4);
  u16* WembF1 = (u16*)alloc(64 * 128 * 2);
  u16* WembF2 = (u16*)alloc(128 * 128 * 2);
  u16* WABf   = (u16*)alloc((size_t)6 * 192 * 256 * 2);
  float* bABf = (float*)alloc(6 * 256 * 4);
  u16* Wm2f   = (u16*)alloc((size_t)6 * 128 * 128 * 2);
  u16* Wu1f   = (u16*)alloc((size_t)6 * 320 * 128 * 2);
  u16* Wu2f   = (u16*)alloc((size_t)6 * 128 * 128 * 2);
  u16* Wdblf  = (u16*)alloc((size_t)128 * 256 * 2);

  hipMemsetAsync(stats, 0, (size_t)NL * 2 * 1024 * 4, stream);

  prep_std<<<dim3(32, 1), 256, 0, stream>>>(embW1, WembF1, 52, 64, 128);
  prep_std<<<dim3(64, 1), 256, 0, stream>>>(embW2, WembF2, 128, 128, 128);
  prep_std<<<dim3(64, 6), 256, 0, stream>>>(m2W, Wm2f, 128, 128, 128);
  prep_std<<<dim3(160, 6), 256, 0, stream>>>(u1W, Wu1f, 257, 320, 128);
  prep_std<<<dim3(64, 6), 256, 0, stream>>>(u2W, Wu2f, 128, 128, 128);
  prep_std<<<dim3(128, 1), 256, 0, stream>>>(dblW, Wdblf, 128, 128, 256);
  prep_AB<<<dim3(192, 6), 256, 0, stream>>>(m1W, m1b, WABf, bABf);
  build_static<<<N_NODES * 64 / 256, 256, 0, stream>>>(u, pos, X0);

  enc_fused<<<512, 256, 0, stream>>>(X0, WembF1, embb1, WembF2, embb2, hB);

  for (int l = 0; l < NL; ++l) {
    const float* S1p = l ? stats + (size_t)(l - 1) * 2048 : nullptr;
    const float* S2p = l ? stats + (size_t)(l - 1) * 2048 + 1024 : nullptr;
    float* S1n = stats + (size_t)l * 2048;
    float* S2n = S1n + 1024;
    gemm2<192, 256, 0, 1, 0, 1><<<512, 256, 0, stream>>>(
        nullptr, 0, X0, hB, S1p, S2p, nullptr,
        WABf + (size_t)l * 192 * 256, bABf + l * 256, ABbuf, 256,
        nullptr, nullptr, nullptr);
    msg_upd<<<512, 256, 0, stream>>>(
        ABbuf, srcI, hB, S1p, S2p, pos,
        Wm2f + (size_t)l * 128 * 128, m2b + l * 128,
        Wu1f + (size_t)l * 320 * 128, u1b + l * 128,
        Wu2f + (size_t)l * 128 * 128, u2b + l * 128,
        S1n, S2n);
  }

  gemm2<128, 256, 1, 1, 0, 0><<<512, 256, 0, stream>>>(
      nullptr, 0, nullptr, hB, stats + (size_t)5 * 2048, stats + (size_t)5 * 2048 + 1024,
      nullptr, Wdblf, dblb, nullptr, 0, x2f, nullptr, nullptr);
  dec_conv<<<N_NODES / 16, 256, 0, stream>>>(x2f, u, c1W, c1b, c2W, c2b, outp);
}